// Round 2
// baseline (14890.280 us; speedup 1.0000x reference)
//
#include <hip/hip_runtime.h>

#define TSEQ 512
#define BATCH 64
#define DIN 1024
#define HID 512
#define G4 2048
#define CHK 64

typedef __attribute__((ext_vector_type(8))) short short8;
typedef __attribute__((ext_vector_type(4))) float floatx4;

__device__ __forceinline__ floatx4 mfma16(short8 a, short8 b, floatx4 c) {
  return __builtin_amdgcn_mfma_f32_16x16x32_bf16(a, b, c, 0, 0, 0);
}

__device__ __forceinline__ unsigned short f2bf(float f) {
  unsigned int u = __float_as_uint(f);
  unsigned int r = (u + 0x7fffu + ((u >> 16) & 1u)) >> 16;
  return (unsigned short)r;
}

__device__ __forceinline__ float sigm(float x) { return 1.f / (1.f + __expf(-x)); }
__device__ __forceinline__ float tanh_f(float x) {
  float xx = fminf(fmaxf(x, -15.f), 15.f);
  float e = __expf(2.f * xx);
  return (e - 1.f) / (e + 1.f);
}

// Convert fp32 x -> bf16 (same [T][B][DIN] layout, k-contiguous for B-fragments)
__global__ void k_convert_x(const float* __restrict__ x, unsigned short* __restrict__ xbf, int n4) {
  int i = blockIdx.x * 256 + threadIdx.x;
  if (i >= n4) return;
  floatx4 v = reinterpret_cast<const floatx4*>(x)[i];
  union { unsigned short us[4]; unsigned long long ull; } pk;
  pk.us[0] = f2bf(v[0]); pk.us[1] = f2bf(v[1]); pk.us[2] = f2bf(v[2]); pk.us[3] = f2bf(v[3]);
  reinterpret_cast<unsigned long long*>(xbf)[i] = pk.ull;
}

// Pre-arrange W [L][2][2048][K] fp32 into bf16 MFMA A-fragment order, rows
// permuted row' = 4*unit + gate (orig row = gate*512 + unit).
__global__ void k_prep_w(const float* __restrict__ W, unsigned short* __restrict__ Wf, int K) {
  int mt = blockIdx.x, kt = blockIdx.y, ld = blockIdx.z;
  int lane = threadIdx.x;
  int rp = mt * 16 + (lane & 15);
  int row = (rp & 3) * HID + (rp >> 2);
  int k0 = kt * 32 + (lane >> 4) * 8;
  const float* src = W + (size_t)ld * G4 * K + (size_t)row * K + k0;
  unsigned short* dst = Wf + (size_t)ld * G4 * K + (((size_t)mt * (K / 32) + kt) * 64 + lane) * 8;
  for (int j = 0; j < 8; ++j) dst[j] = f2bf(src[j]);
}

__global__ void k_prep_bias(const float* __restrict__ bih, const float* __restrict__ bhh,
                            float* __restrict__ biasf) {
  int i = blockIdx.x * 256 + threadIdx.x;  // 0 .. 4*2048-1
  int ld = i >> 11;
  int rp = i & 2047;
  int row = (rp & 3) * HID + (rp >> 2);
  biasf[i] = bih[ld * G4 + row] + bhh[ld * G4 + row];
}

// Input projection for one T-chunk (both directions).
// pre is TRANSPOSED: pre[dir][tloc][b][g']  (fp32) so the recurrence kernel
// can init its accumulators with float4 loads.
__global__ __launch_bounds__(256, 2) void k_proj(
    const unsigned short* __restrict__ xin,   // [T][B][DIN] bf16
    const unsigned short* __restrict__ Wf,    // this layer: [2][G4*DIN] frag order
    const float* __restrict__ biasf,          // this layer: [2][G4] permuted
    float* __restrict__ pre,                  // [2][CHK][BATCH][G4]
    int t0) {
  const int dir = blockIdx.z;
  const int w = threadIdx.x >> 6;
  const int lane = threadIdx.x & 63;
  const int quad = lane >> 4, col = lane & 15;
  const int tloc = blockIdx.y * 4 + w;
  const int tg = dir ? (TSEQ - 1 - (t0 + tloc)) : (t0 + tloc);
  const unsigned short* Wd = Wf + (size_t)dir * G4 * DIN;
  const unsigned short* xrow = xin + (size_t)tg * BATCH * DIN;

  floatx4 acc[8][4];
#pragma unroll
  for (int mi = 0; mi < 8; ++mi)
#pragma unroll
    for (int ni = 0; ni < 4; ++ni) acc[mi][ni] = (floatx4){0.f, 0.f, 0.f, 0.f};

#pragma unroll 4
  for (int kt = 0; kt < 32; ++kt) {
    short8 bfr[4];
#pragma unroll
    for (int ni = 0; ni < 4; ++ni) {
      int b = ni * 16 + col;
      bfr[ni] = *reinterpret_cast<const short8*>(xrow + (size_t)b * DIN + kt * 32 + quad * 8);
    }
#pragma unroll
    for (int mi = 0; mi < 8; ++mi) {
      size_t mt = (size_t)(blockIdx.x * 8 + mi);
      short8 afr = *reinterpret_cast<const short8*>(Wd + ((mt * 32 + kt) * 64 + lane) * 8);
#pragma unroll
      for (int ni = 0; ni < 4; ++ni) acc[mi][ni] = mfma16(afr, bfr[ni], acc[mi][ni]);
    }
  }

#pragma unroll
  for (int mi = 0; mi < 8; ++mi) {
    int gbase = blockIdx.x * 128 + mi * 16 + quad * 4;
    floatx4 bv = *reinterpret_cast<const floatx4*>(biasf + dir * G4 + gbase);
#pragma unroll
    for (int ni = 0; ni < 4; ++ni) {
      int b = ni * 16 + col;
      floatx4 v;
#pragma unroll
      for (int r = 0; r < 4; ++r) v[r] = acc[mi][ni][r] + bv[r];
      *reinterpret_cast<floatx4*>(
          pre + (((size_t)dir * CHK + tloc) * BATCH + b) * G4 + gbase) = v;
    }
  }
}

// Persistent recurrence kernel: one launch runs CHK=64 steps for both dirs.
// Grid (64, 2) = 128 blocks (co-resident on 256 CUs). Per-direction
// device-scope barrier between steps (monotonic counter, 64 arrivals/step).
// Whh fragments for this block are held in registers for all 64 steps;
// cell state lives in registers (cst only read/written at chunk boundaries).
__global__ __launch_bounds__(256, 1) void k_rec_chunk(
    const unsigned short* __restrict__ Whhf,  // this layer: [2][G4*HID] frag order
    const float* __restrict__ pre,            // [2][CHK][BATCH][G4]
    unsigned short* act1bf,                   // [T][B][DIN] bf16
    unsigned short* hT2,                      // [2 slots][2 dir][B][HID] bf16
    float* cst,                               // [2 layer][2 dir][HID][B] fp32
    float* __restrict__ dout,                 // [T][B][DIN] fp32
    unsigned int* __restrict__ bar,           // 2 counters, 256B apart
    int s0, int layer, int base_steps) {
  const int dir = blockIdx.y;
  const int gb = blockIdx.x;  // 0..63
  const int lane = threadIdx.x & 63;
  const int w = threadIdx.x >> 6;
  const int quad = lane >> 4, col = lane & 15;
  const int b = w * 16 + col;

  // hoist this block's Whh fragments into registers (32 x short8 = 128 VGPR)
  const unsigned short* Wd = Whhf + (size_t)dir * G4 * HID;
  short8 wreg[2][16];
#pragma unroll
  for (int mi = 0; mi < 2; ++mi)
#pragma unroll
    for (int kt = 0; kt < 16; ++kt) {
      size_t mt = (size_t)(gb * 2 + mi);
      wreg[mi][kt] = *reinterpret_cast<const short8*>(Wd + ((mt * 16 + kt) * 64 + lane) * 8);
    }

  float* cl = cst + ((size_t)layer * 2 + dir) * HID * BATCH;
  float creg[2];
#pragma unroll
  for (int mi = 0; mi < 2; ++mi) {
    int u = gb * 8 + mi * 4 + quad;
    creg[mi] = (s0 > 0) ? cl[u * BATCH + b] : 0.f;
  }

  unsigned int* cnt = bar + dir * 64;

  for (int j = 0; j < CHK; ++j) {
    const int s = s0 + j;
    const int t = dir ? (TSEQ - 1 - s) : s;

    floatx4 acc[2];
#pragma unroll
    for (int mi = 0; mi < 2; ++mi)
      acc[mi] = *reinterpret_cast<const floatx4*>(
          pre + (((size_t)dir * CHK + j) * BATCH + b) * G4 + gb * 32 + mi * 16 + quad * 4);

    if (s > 0) {
      const unsigned short* hprev;
      int hstride;
      if (layer == 0) {
        int tp = dir ? t + 1 : t - 1;
        hprev = act1bf + (size_t)tp * BATCH * DIN + dir * HID;
        hstride = DIN;
      } else {
        hprev = hT2 + (size_t)(((s - 1) & 1) * 2 + dir) * BATCH * HID;
        hstride = HID;
      }
#pragma unroll
      for (int kt = 0; kt < 16; ++kt) {
        short8 bfr = *reinterpret_cast<const short8*>(hprev + (size_t)b * hstride + kt * 32 + quad * 8);
        acc[0] = mfma16(wreg[0][kt], bfr, acc[0]);
        acc[1] = mfma16(wreg[1][kt], bfr, acc[1]);
      }
    }

#pragma unroll
    for (int mi = 0; mi < 2; ++mi) {
      int u = gb * 8 + mi * 4 + quad;
      float si = sigm(acc[mi][0]);
      float sf = sigm(acc[mi][1]);
      float tg = tanh_f(acc[mi][2]);
      float so = sigm(acc[mi][3]);
      float c = creg[mi] * si + sf * tg;
      float h = tanh_f(c) * so;
      creg[mi] = c;
      if (layer == 0) {
        act1bf[((size_t)t * BATCH + b) * DIN + dir * HID + u] = f2bf(h);
      } else {
        hT2[((size_t)((s & 1) * 2 + dir) * BATCH + b) * HID + u] = f2bf(h);
        dout[((size_t)t * BATCH + b) * DIN + dir * HID + u] = h;
      }
    }

    // device-scope barrier across this direction's 64 blocks
    __syncthreads();
    if (threadIdx.x == 0) {
      __threadfence();
      __hip_atomic_fetch_add(cnt, 1u, __ATOMIC_RELEASE, __HIP_MEMORY_SCOPE_AGENT);
      const unsigned int target = (unsigned int)(64 * (base_steps + j + 1));
      while (__hip_atomic_load(cnt, __ATOMIC_ACQUIRE, __HIP_MEMORY_SCOPE_AGENT) < target) {}
      __threadfence();
    }
    __syncthreads();
  }

  // persist cell state for the next chunk
#pragma unroll
  for (int mi = 0; mi < 2; ++mi) {
    int u = gb * 8 + mi * 4 + quad;
    cl[u * BATCH + b] = creg[mi];
  }
}

extern "C" void kernel_launch(void* const* d_in, const int* in_sizes, int n_in,
                              void* d_out, int out_size, void* d_ws, size_t ws_size,
                              hipStream_t stream) {
  const float* x = (const float*)d_in[0];
  const float* W_ih = (const float*)d_in[1];
  const float* b_ih = (const float*)d_in[2];
  const float* W_hh = (const float*)d_in[3];
  const float* b_hh = (const float*)d_in[4];
  float* dout = (float*)d_out;

  char* p = (char*)d_ws;
  auto alloc = [&](size_t bytes) {
    char* r = p;
    p += (bytes + 255) & ~(size_t)255;
    return r;
  };
  unsigned short* xbf    = (unsigned short*)alloc((size_t)TSEQ * BATCH * DIN * 2);
  unsigned short* act1bf = (unsigned short*)alloc((size_t)TSEQ * BATCH * DIN * 2);
  float*          pre    = (float*)alloc((size_t)2 * CHK * G4 * BATCH * 4);
  unsigned short* Wihf   = (unsigned short*)alloc((size_t)4 * G4 * DIN * 2);
  unsigned short* Whhf   = (unsigned short*)alloc((size_t)4 * G4 * HID * 2);
  float*          biasf  = (float*)alloc((size_t)4 * G4 * 4);
  float*          cst    = (float*)alloc((size_t)4 * HID * BATCH * 4);
  unsigned short* hT2    = (unsigned short*)alloc((size_t)4 * BATCH * HID * 2);
  unsigned int*   bar    = (unsigned int*)alloc(512);

  size_t required = (size_t)(p - (char*)d_ws);
  if (ws_size < required) return;  // fail visibly rather than corrupt memory

  hipMemsetAsync(bar, 0, 512, stream);

  int n4 = TSEQ * BATCH * DIN / 4;
  k_convert_x<<<dim3((n4 + 255) / 256), dim3(256), 0, stream>>>(x, xbf, n4);
  k_prep_w<<<dim3(G4 / 16, DIN / 32, 4), dim3(64), 0, stream>>>(W_ih, Wihf, DIN);
  k_prep_w<<<dim3(G4 / 16, HID / 32, 4), dim3(64), 0, stream>>>(W_hh, Whhf, HID);
  k_prep_bias<<<dim3(32), dim3(256), 0, stream>>>(b_ih, b_hh, biasf);

  for (int l = 0; l < 2; ++l) {
    const unsigned short* xin = l ? act1bf : xbf;
    const unsigned short* Wfl = Wihf + (size_t)l * 2 * G4 * DIN;
    const unsigned short* Whl = Whhf + (size_t)l * 2 * G4 * HID;
    const float* bfl = biasf + (size_t)l * 2 * G4;
    for (int c = 0; c < TSEQ / CHK; ++c) {
      k_proj<<<dim3(G4 / 128, CHK / 4, 2), dim3(256), 0, stream>>>(xin, Wfl, bfl, pre, c * CHK);
      k_rec_chunk<<<dim3(64, 2), dim3(256), 0, stream>>>(
          Whl, pre, act1bf, hT2, cst, dout, bar, c * CHK, l, (l * 8 + c) * CHK);
    }
  }
  (void)in_sizes; (void)n_in; (void)out_size;
}

// Round 3
// 11124.187 us; speedup vs baseline: 1.3385x; 1.3385x over previous
//
#include <hip/hip_runtime.h>

#define TSEQ 512
#define BATCH 64
#define DIN 1024
#define HID 512
#define G4 2048
#define CHK 64

typedef __attribute__((ext_vector_type(8))) short short8;
typedef __attribute__((ext_vector_type(4))) float floatx4;

__device__ __forceinline__ floatx4 mfma16(short8 a, short8 b, floatx4 c) {
  return __builtin_amdgcn_mfma_f32_16x16x32_bf16(a, b, c, 0, 0, 0);
}

__device__ __forceinline__ unsigned short f2bf(float f) {
  unsigned int u = __float_as_uint(f);
  unsigned int r = (u + 0x7fffu + ((u >> 16) & 1u)) >> 16;
  return (unsigned short)r;
}
__device__ __forceinline__ float bf2f(unsigned short s) {
  return __uint_as_float(((unsigned int)s) << 16);
}

__device__ __forceinline__ float sigm(float x) { return 1.f / (1.f + __expf(-x)); }
__device__ __forceinline__ float tanh_f(float x) {
  float xx = fminf(fmaxf(x, -15.f), 15.f);
  float e = __expf(2.f * xx);
  return (e - 1.f) / (e + 1.f);
}

// Convert fp32 x -> bf16 (same [T][B][DIN] layout, k-contiguous for B-fragments)
__global__ void k_convert_x(const float* __restrict__ x, unsigned short* __restrict__ xbf, int n4) {
  int i = blockIdx.x * 256 + threadIdx.x;
  if (i >= n4) return;
  floatx4 v = reinterpret_cast<const floatx4*>(x)[i];
  union { unsigned short us[4]; unsigned long long ull; } pk;
  pk.us[0] = f2bf(v[0]); pk.us[1] = f2bf(v[1]); pk.us[2] = f2bf(v[2]); pk.us[3] = f2bf(v[3]);
  reinterpret_cast<unsigned long long*>(xbf)[i] = pk.ull;
}

// Pre-arrange W [L][2][2048][K] fp32 into bf16 MFMA A-fragment order, rows
// permuted row' = 4*unit + gate (orig row = gate*512 + unit).
__global__ void k_prep_w(const float* __restrict__ W, unsigned short* __restrict__ Wf, int K) {
  int mt = blockIdx.x, kt = blockIdx.y, ld = blockIdx.z;
  int lane = threadIdx.x;
  int rp = mt * 16 + (lane & 15);
  int row = (rp & 3) * HID + (rp >> 2);
  int k0 = kt * 32 + (lane >> 4) * 8;
  const float* src = W + (size_t)ld * G4 * K + (size_t)row * K + k0;
  unsigned short* dst = Wf + (size_t)ld * G4 * K + (((size_t)mt * (K / 32) + kt) * 64 + lane) * 8;
  for (int j = 0; j < 8; ++j) dst[j] = f2bf(src[j]);
}

__global__ void k_prep_bias(const float* __restrict__ bih, const float* __restrict__ bhh,
                            float* __restrict__ biasf) {
  int i = blockIdx.x * 256 + threadIdx.x;  // 0 .. 4*2048-1
  int ld = i >> 11;
  int rp = i & 2047;
  int row = (rp & 3) * HID + (rp >> 2);
  biasf[i] = bih[ld * G4 + row] + bhh[ld * G4 + row];
}

// Input projection for one T-chunk (both directions).
// pre is bf16, layout pre[dir][tloc][b][g'] so the recurrence kernel inits
// accumulators with one 8B load per m-tile.
__global__ __launch_bounds__(256, 2) void k_proj(
    const unsigned short* __restrict__ xin,   // [T][B][DIN] bf16
    const unsigned short* __restrict__ Wf,    // this layer: [2][G4*DIN] frag order
    const float* __restrict__ biasf,          // this layer: [2][G4] permuted
    unsigned short* __restrict__ pre,         // [2][CHK][BATCH][G4] bf16
    int t0) {
  const int dir = blockIdx.z;
  const int w = threadIdx.x >> 6;
  const int lane = threadIdx.x & 63;
  const int quad = lane >> 4, col = lane & 15;
  const int tloc = blockIdx.y * 4 + w;
  const int tg = dir ? (TSEQ - 1 - (t0 + tloc)) : (t0 + tloc);
  const unsigned short* Wd = Wf + (size_t)dir * G4 * DIN;
  const unsigned short* xrow = xin + (size_t)tg * BATCH * DIN;

  floatx4 acc[8][4];
#pragma unroll
  for (int mi = 0; mi < 8; ++mi)
#pragma unroll
    for (int ni = 0; ni < 4; ++ni) acc[mi][ni] = (floatx4){0.f, 0.f, 0.f, 0.f};

#pragma unroll 4
  for (int kt = 0; kt < 32; ++kt) {
    short8 bfr[4];
#pragma unroll
    for (int ni = 0; ni < 4; ++ni) {
      int b = ni * 16 + col;
      bfr[ni] = *reinterpret_cast<const short8*>(xrow + (size_t)b * DIN + kt * 32 + quad * 8);
    }
#pragma unroll
    for (int mi = 0; mi < 8; ++mi) {
      size_t mt = (size_t)(blockIdx.x * 8 + mi);
      short8 afr = *reinterpret_cast<const short8*>(Wd + ((mt * 32 + kt) * 64 + lane) * 8);
#pragma unroll
      for (int ni = 0; ni < 4; ++ni) acc[mi][ni] = mfma16(afr, bfr[ni], acc[mi][ni]);
    }
  }

#pragma unroll
  for (int mi = 0; mi < 8; ++mi) {
    int gbase = blockIdx.x * 128 + mi * 16 + quad * 4;
    floatx4 bv = *reinterpret_cast<const floatx4*>(biasf + dir * G4 + gbase);
#pragma unroll
    for (int ni = 0; ni < 4; ++ni) {
      int b = ni * 16 + col;
      union { unsigned short us[4]; unsigned long long u; } pk;
#pragma unroll
      for (int r = 0; r < 4; ++r) pk.us[r] = f2bf(acc[mi][ni][r] + bv[r]);
      *reinterpret_cast<unsigned long long*>(
          pre + (((size_t)dir * CHK + tloc) * BATCH + b) * G4 + gbase) = pk.u;
    }
  }
}

// Persistent recurrence kernel: one launch runs CHK=64 steps for both dirs.
// Grid (64, 2) = 128 blocks, 1 per CU. Cross-block h exchange goes through
// hex[dir][j][gb][b][8u]: step-unique, fully block-owned cache lines, so
// readers' first-touch loads are always fresh and NO acquire/L2-invalidate is
// needed. Arrival: agent-scope RELEASE fetch_add (waitcnt+wbl2, no inv).
// Poll: agent-scope RELAXED atomic load (coherence-point load, ockl pattern).
__global__ __launch_bounds__(256, 1) void k_rec_chunk(
    const unsigned short* __restrict__ Whhf,  // this layer: [2][G4*HID] frag order
    const unsigned short* __restrict__ pre,   // [2][CHK][BATCH][G4] bf16
    unsigned short* __restrict__ act1bf,      // [T][B][DIN] bf16 (layer-1 output)
    unsigned short* __restrict__ hex,         // [2][CHK][64 gb][64 b][8] bf16
    float* cst,                               // [2 layer][2 dir][HID][B] fp32
    float* __restrict__ dout,                 // [T][B][DIN] fp32
    unsigned int* __restrict__ bar,           // 2 counters, 256B apart
    int s0, int layer, int base_steps) {
  const int dir = blockIdx.y;
  const int gb = blockIdx.x;  // 0..63
  const int lane = threadIdx.x & 63;
  const int w = threadIdx.x >> 6;
  const int quad = lane >> 4, col = lane & 15;
  const int b = w * 16 + col;

  // hoist this block's Whh fragments into registers (32 x short8 = 128 VGPR)
  const unsigned short* Wd = Whhf + (size_t)dir * G4 * HID;
  short8 wreg[2][16];
#pragma unroll
  for (int mi = 0; mi < 2; ++mi)
#pragma unroll
    for (int kt = 0; kt < 16; ++kt) {
      size_t mt = (size_t)(gb * 2 + mi);
      wreg[mi][kt] = *reinterpret_cast<const short8*>(Wd + ((mt * 16 + kt) * 64 + lane) * 8);
    }

  float* cl = cst + ((size_t)layer * 2 + dir) * HID * BATCH;
  float creg[2];
#pragma unroll
  for (int mi = 0; mi < 2; ++mi) {
    int u = gb * 8 + mi * 4 + quad;
    creg[mi] = (s0 > 0) ? cl[u * BATCH + b] : 0.f;
  }

  unsigned int* cnt = bar + dir * 64;
  unsigned short* hexd = hex + (size_t)dir * CHK * 64 * BATCH * 8;

  for (int j = 0; j < CHK; ++j) {
    const int s = s0 + j;
    const int t = dir ? (TSEQ - 1 - s) : s;

    // accumulator init from bf16 pre: one 8B load per m-tile
    floatx4 acc[2];
    const unsigned short* prow =
        pre + (((size_t)dir * CHK + j) * BATCH + b) * G4 + gb * 32;
#pragma unroll
    for (int mi = 0; mi < 2; ++mi) {
      union { unsigned short us[4]; unsigned long long u; } pk;
      pk.u = *reinterpret_cast<const unsigned long long*>(prow + mi * 16 + quad * 4);
#pragma unroll
      for (int r = 0; r < 4; ++r) acc[mi][r] = bf2f(pk.us[r]);
    }

    if (s > 0) {
      const int jp = (j + CHK - 1) & (CHK - 1);  // j-1; j==0 wraps to prev launch's slot 63
      const unsigned short* hj = hexd + (size_t)jp * 64 * BATCH * 8;
#pragma unroll
      for (int kt = 0; kt < 16; ++kt) {
        // granule g' = kt*4+quad holds units g'*8..g'*8+7 for batch b
        short8 bfr = *reinterpret_cast<const short8*>(
            hj + ((size_t)(kt * 4 + quad) * BATCH + b) * 8);
        acc[0] = mfma16(wreg[0][kt], bfr, acc[0]);
        acc[1] = mfma16(wreg[1][kt], bfr, acc[1]);
      }
    }

    unsigned short* hslot = hexd + (((size_t)j * 64 + gb) * BATCH + b) * 8;
#pragma unroll
    for (int mi = 0; mi < 2; ++mi) {
      int u = gb * 8 + mi * 4 + quad;
      float si = sigm(acc[mi][0]);
      float sf = sigm(acc[mi][1]);
      float tg = tanh_f(acc[mi][2]);
      float so = sigm(acc[mi][3]);
      float c = creg[mi] * si + sf * tg;
      float h = tanh_f(c) * so;
      creg[mi] = c;
      unsigned short hb = f2bf(h);
      hslot[mi * 4 + quad] = hb;  // block-owned exchange granule
      if (layer == 0) {
        act1bf[((size_t)t * BATCH + b) * DIN + dir * HID + u] = hb;
      } else {
        dout[((size_t)t * BATCH + b) * DIN + dir * HID + u] = h;
      }
    }

    // barrier: release arrival (wbl2, no inv), relaxed poll (no inv)
    __syncthreads();
    if (threadIdx.x == 0) {
      __hip_atomic_fetch_add(cnt, 1u, __ATOMIC_RELEASE, __HIP_MEMORY_SCOPE_AGENT);
      if (j + 1 < CHK) {
        const unsigned int target = (unsigned int)(64 * (base_steps + j + 1));
        while (__hip_atomic_load(cnt, __ATOMIC_RELAXED, __HIP_MEMORY_SCOPE_AGENT) < target) {
          __builtin_amdgcn_s_sleep(1);
        }
      }
    }
    __syncthreads();
  }

  // persist cell state for the next chunk
#pragma unroll
  for (int mi = 0; mi < 2; ++mi) {
    int u = gb * 8 + mi * 4 + quad;
    cl[u * BATCH + b] = creg[mi];
  }
}

extern "C" void kernel_launch(void* const* d_in, const int* in_sizes, int n_in,
                              void* d_out, int out_size, void* d_ws, size_t ws_size,
                              hipStream_t stream) {
  const float* x = (const float*)d_in[0];
  const float* W_ih = (const float*)d_in[1];
  const float* b_ih = (const float*)d_in[2];
  const float* W_hh = (const float*)d_in[3];
  const float* b_hh = (const float*)d_in[4];
  float* dout = (float*)d_out;

  char* p = (char*)d_ws;
  auto alloc = [&](size_t bytes) {
    char* r = p;
    p += (bytes + 255) & ~(size_t)255;
    return r;
  };
  unsigned short* xbf    = (unsigned short*)alloc((size_t)TSEQ * BATCH * DIN * 2);
  unsigned short* act1bf = (unsigned short*)alloc((size_t)TSEQ * BATCH * DIN * 2);
  unsigned short* pre    = (unsigned short*)alloc((size_t)2 * CHK * BATCH * G4 * 2);
  unsigned short* Wihf   = (unsigned short*)alloc((size_t)4 * G4 * DIN * 2);
  unsigned short* Whhf   = (unsigned short*)alloc((size_t)4 * G4 * HID * 2);
  float*          biasf  = (float*)alloc((size_t)4 * G4 * 4);
  float*          cst    = (float*)alloc((size_t)4 * HID * BATCH * 4);
  unsigned short* hex    = (unsigned short*)alloc((size_t)2 * CHK * 64 * BATCH * 8 * 2);
  unsigned int*   bar    = (unsigned int*)alloc(512);

  size_t required = (size_t)(p - (char*)d_ws);
  if (ws_size < required) return;  // fail visibly rather than corrupt memory

  hipMemsetAsync(bar, 0, 512, stream);

  int n4 = TSEQ * BATCH * DIN / 4;
  k_convert_x<<<dim3((n4 + 255) / 256), dim3(256), 0, stream>>>(x, xbf, n4);
  k_prep_w<<<dim3(G4 / 16, DIN / 32, 4), dim3(64), 0, stream>>>(W_ih, Wihf, DIN);
  k_prep_w<<<dim3(G4 / 16, HID / 32, 4), dim3(64), 0, stream>>>(W_hh, Whhf, HID);
  k_prep_bias<<<dim3(32), dim3(256), 0, stream>>>(b_ih, b_hh, biasf);

  for (int l = 0; l < 2; ++l) {
    const unsigned short* xin = l ? act1bf : xbf;
    const unsigned short* Wfl = Wihf + (size_t)l * 2 * G4 * DIN;
    const unsigned short* Whl = Whhf + (size_t)l * 2 * G4 * HID;
    const float* bfl = biasf + (size_t)l * 2 * G4;
    for (int c = 0; c < TSEQ / CHK; ++c) {
      k_proj<<<dim3(G4 / 128, CHK / 4, 2), dim3(256), 0, stream>>>(xin, Wfl, bfl, pre, c * CHK);
      k_rec_chunk<<<dim3(64, 2), dim3(256), 0, stream>>>(
          Whl, pre, act1bf, hex, cst, dout, bar, c * CHK, l, (l * 8 + c) * CHK);
    }
  }
  (void)in_sizes; (void)n_in; (void)out_size;
}